// Round 9
// baseline (227.668 us; speedup 1.0000x reference)
//
#include <hip/hip_runtime.h>
#include <math.h>

// Problem constants (match reference)
#define NB 128
#define NF 2048
#define NE 256
#define NF4 (NE / 4)   // 64 float4 per 256-float row

#define WAVES_PER_BLOCK 4
#define FACTS_PER_WAVE 16
#define FACTS_PER_BLOCK 64
#define CHUNKS_PER_B 32
#define NPASS 4                                  // 4 facts per pass, 4 passes
#define NSLOT (CHUNKS_PER_B * WAVES_PER_BLOCK)   // 128 dmin slots per b
#define GRID (NB * CHUNKS_PER_B)                 // 4096 blocks
#define CTR_OFF (NB * NSLOT)                     // float-index of done-counter in ws

// Branch-and-bound threshold. expf(-x) == 0.0f exactly for x > ~104
// (e^-104 < 2^-150 rounds to +0). Squared distance accumulates
// non-negatively over dims, so ANY prefix sum > T => full d > T => score is
// exactly 0.0f in BOTH reference and ours. T=110 leaves margin over 104.
// Three stages, each an exact monotone bound (correctness never depends on
// the data distribution, only speed does):
//   A: 64-dim prefix (256 B/row) screens all valid facts  (~21% survive)
//   B: 128-dim prefix (re-reads A's 256 B from L2 + 256 B new) (~2e-6)
//   C: full 768-dim exact distance, folded into the running min
#define THRESH 110.0f

__device__ __forceinline__ float sqd4(float4 a, float4 b) {
    float dx = a.x - b.x;
    float dy = a.y - b.y;
    float dz = a.z - b.z;
    float dw = a.w - b.w;
    return dx * dx + dy * dy + dz * dz + dw * dw;
}

// Single fused kernel. Per block: 16 lanes per fact (seg = lane&15), 4 facts
// per pass (sub = lane>>4). Stage A prefetches ALL 4 pass-rows up-front
// (4 independent loads/lane -> one vmcnt drain instead of 4; indices clamped
// to nb-1, clamped duplicates excluded from the mask by the f<nb predicate).
// Stage-B candidates are pulled 4-at-a-time from the wave-uniform mask.
// Finish is fused via last-block-done: every block (live or dead waves alike)
// writes its 4 per-wave dmin slots, then releases its writes with
// __threadfence() + device-scope atomicAdd on a counter (zeroed each call by
// a 4-byte hipMemsetAsync node); the last block reduces all slots with
// agent-scope atomic loads (cross-XCD safe) and writes out. Which block runs
// last varies, but the reduced min-set is identical -> deterministic output.
__global__ __launch_bounds__(256, 8) void nkb_fused_kernel(
    const float* __restrict__ rel,
    const float* __restrict__ arg1,
    const float* __restrict__ arg2,
    const float* __restrict__ fact_rel,
    const float* __restrict__ fact_arg1,
    const float* __restrict__ fact_arg2,
    const int* __restrict__ nb_facts,
    float* __restrict__ ws,
    float* __restrict__ out)
{
    const int b = blockIdx.x >> 5;        // / CHUNKS_PER_B
    const int chunk = blockIdx.x & 31;    // % CHUNKS_PER_B
    const int nb = nb_facts[b];
    const int tid = threadIdx.x;
    const int wave = tid >> 6;
    const int lane = tid & 63;
    const int sub = lane >> 4;   // which of the 4 facts in a pass/batch
    const int seg = lane & 15;   // float4 segment within a 64-dim half-prefix

    const int fbeg = chunk * FACTS_PER_BLOCK + wave * FACTS_PER_WAVE;
    float dmin = INFINITY;

    if (fbeg < nb) {
        const int fmax = nb - 1;  // nb >= 1 here
        // Query prefix: q0 covers dims [4seg,4seg+4) (stage A),
        //               q1 covers dims [64+4seg, 64+4seg+4) (stage B).
        const float4* qr = reinterpret_cast<const float4*>(rel + (size_t)b * NE);
        const float4 q0 = qr[seg];
        const float4 q1 = qr[seg + 16];

        const float4* fr = reinterpret_cast<const float4*>(fact_rel + (size_t)b * NF * NE);

        // ---- Stage A: 64-dim prefix, all 4 pass-rows prefetched up-front ----
        float4 P[NPASS];
        #pragma unroll
        for (int k = 0; k < NPASS; ++k) {
            const int f = min(fbeg + 4 * k + sub, fmax);
            P[k] = fr[(size_t)f * NF4 + seg];
        }

        unsigned int maskA = 0;  // bit p: fact fbeg+p survives stage A (uniform)
        #pragma unroll
        for (int k = 0; k < NPASS; ++k) {
            float acc = sqd4(q0, P[k]);
            #pragma unroll
            for (int s = 1; s < 16; s <<= 1) acc += __shfl_xor(acc, s);

            const bool cand = (acc <= THRESH) && (fbeg + 4 * k + sub < nb);
            const unsigned long long bal = __ballot(cand);
            const unsigned int bits =
                  (unsigned int)( (bal        & 1ull)
                               | ((bal >> 16) & 1ull) << 1
                               | ((bal >> 32) & 1ull) << 2
                               | ((bal >> 48) & 1ull) << 3);
            maskA |= bits << (4 * k);  // bit index 4k+sub
        }

        // ---- Stage B: 128-dim prefix for stage-A survivors, 4 at a time ----
        unsigned int maskB = 0;  // survivors of the 128-dim screen (uniform)
        while (maskA) {
            unsigned int m = maskA;
            const int i0 = __ffs(m) - 1; m &= m - 1;   // valid (loop guard)
            const int i1 = __ffs(m) - 1; m &= m - 1;   // may be -1
            const int i2 = __ffs(m) - 1; m &= m - 1;
            const int i3 = __ffs(m) - 1; m &= m - 1;
            maskA = m;

            const int idx = (sub == 0) ? i0 : (sub == 1) ? i1 : (sub == 2) ? i2 : i3;
            const bool act = (idx >= 0);
            const int f = fbeg + (act ? idx : i0);  // inactive lanes dup i0 (cache hit)
            const size_t base = (size_t)f * NF4 + seg;
            const float4 P0 = fr[base];        // stage-A bytes: L1/L2 hot
            const float4 P1 = fr[base + 16];   // new 256 B (dims 64..127)
            float acc = sqd4(q0, P0) + sqd4(q1, P1);
            #pragma unroll
            for (int s = 1; s < 16; s <<= 1) acc += __shfl_xor(acc, s);

            const bool candB = act && (acc <= THRESH);
            const unsigned long long bal = __ballot(candB);
            // Map group verdicts back to fact-bit positions (all uniform).
            if ( bal        & 1ull) maskB |= 1u << ((unsigned)i0 & 31u);
            if ((bal >> 16) & 1ull) maskB |= 1u << ((unsigned)i1 & 31u);
            if ((bal >> 32) & 1ull) maskB |= 1u << ((unsigned)i2 & 31u);
            if ((bal >> 48) & 1ull) maskB |= 1u << ((unsigned)i3 & 31u);
        }

        // ---- Stage C: exact full 768-dim distance (wave-uniform, ~never) ----
        if (maskB) {
            const float4* qa1 = reinterpret_cast<const float4*>(arg1 + (size_t)b * NE);
            const float4* qa2 = reinterpret_cast<const float4*>(arg2 + (size_t)b * NE);
            const float4* fa1 = reinterpret_cast<const float4*>(fact_arg1 + (size_t)b * NF * NE);
            const float4* fa2 = reinterpret_cast<const float4*>(fact_arg2 + (size_t)b * NF * NE);
            const float4 qfr  = qr [lane];
            const float4 qf1  = qa1[lane];
            const float4 qf2  = qa2[lane];
            while (maskB) {
                const int p = __ffs(maskB) - 1;
                maskB &= maskB - 1;
                const size_t base = (size_t)(fbeg + p) * NF4 + lane;
                float acc = sqd4(qfr, fr[base]) + sqd4(qf1, fa1[base]) + sqd4(qf2, fa2[base]);
                #pragma unroll
                for (int s = 1; s < 64; s <<= 1) acc += __shfl_xor(acc, s);
                dmin = fminf(dmin, acc);
            }
        }
    }

    // Per-wave slot write, [b][slot] layout (512B contiguous per b).
    if (lane == 0) ws[(size_t)b * NSLOT + chunk * WAVES_PER_BLOCK + wave] = dmin;

    // ---- Last-block-done fused finish ----
    __shared__ int s_last;
    __syncthreads();
    if (tid == 0) {
        __threadfence();  // release: make this block's slot writes visible device-wide
        unsigned int* ctr = reinterpret_cast<unsigned int*>(ws + CTR_OFF);
        const unsigned int old =
            __hip_atomic_fetch_add(ctr, 1u, __ATOMIC_ACQ_REL, __HIP_MEMORY_SCOPE_AGENT);
        s_last = (old == GRID - 1);
    }
    __syncthreads();
    if (!s_last) return;

    // Last block: reduce all 128 slots of each b; agent-scope atomic loads
    // bypass non-coherent caches (per-XCD L2s). 4 waves x 32 b's each.
    __threadfence();
    for (int i = 0; i < NB / WAVES_PER_BLOCK; ++i) {
        const int b2 = wave * (NB / WAVES_PER_BLOCK) + i;
        const float* base = ws + (size_t)b2 * NSLOT;
        float m = fminf(
            __hip_atomic_load(base + lane,      __ATOMIC_RELAXED, __HIP_MEMORY_SCOPE_AGENT),
            __hip_atomic_load(base + 64 + lane, __ATOMIC_RELAXED, __HIP_MEMORY_SCOPE_AGENT));
        #pragma unroll
        for (int s = 1; s < 64; s <<= 1) m = fminf(m, __shfl_xor(m, s));
        if (lane == 0) {
            // No candidates anywhere (incl. nb==0): m=+inf -> output exactly 0.
            out[b2] = isfinite(m) ? expf(-m) : 0.0f;
        }
    }
}

extern "C" void kernel_launch(void* const* d_in, const int* in_sizes, int n_in,
                              void* d_out, int out_size, void* d_ws, size_t ws_size,
                              hipStream_t stream) {
    const float* rel       = (const float*)d_in[0];
    const float* arg1      = (const float*)d_in[1];
    const float* arg2      = (const float*)d_in[2];
    const float* fact_rel  = (const float*)d_in[3];
    const float* fact_arg1 = (const float*)d_in[4];
    const float* fact_arg2 = (const float*)d_in[5];
    const int*   nb_facts  = (const int*)d_in[6];
    float* out = (float*)d_out;
    float* ws  = (float*)d_ws;

    // Zero the done-counter (4 B) every call -> deterministic across graph
    // replays (hipMemsetAsync is graph-capturable; harness uses it itself).
    hipMemsetAsync(ws + CTR_OFF, 0, sizeof(unsigned int), stream);

    // Fused: two-stage prefix screen + exact fallback + last-block finish.
    nkb_fused_kernel<<<GRID, 256, 0, stream>>>(rel, arg1, arg2,
                                               fact_rel, fact_arg1, fact_arg2,
                                               nb_facts, ws, out);
}

// Round 10
// 16.927 us; speedup vs baseline: 13.4503x; 13.4503x over previous
//
#include <hip/hip_runtime.h>
#include <math.h>

// Problem constants (match reference)
#define NB 128
#define NF 2048
#define NE 256
#define NF4 (NE / 4)   // 64 float4 per 256-float row

#define WAVES_PER_BLOCK 4
#define FACTS_PER_WAVE 16
#define FACTS_PER_BLOCK 64
#define CHUNKS_PER_B 32
#define NPASS 4                                  // 4 facts per pass, 4 passes
#define NSLOT (CHUNKS_PER_B * WAVES_PER_BLOCK)   // 128 dmin slots per b

// Branch-and-bound threshold. expf(-x) == 0.0f exactly for x > ~104
// (e^-104 < 2^-150 rounds to +0). Squared distance accumulates
// non-negatively over dims, so ANY prefix sum > T => full d > T => score is
// exactly 0.0f in BOTH reference and ours. T=110 leaves margin over 104.
// Three stages, each an exact monotone bound (correctness never depends on
// the data distribution, only speed does):
//   A: 64-dim prefix (256 B/row) screens all valid facts  (~21% survive)
//   B: 128-dim prefix (re-reads A's 256 B from L2 + 256 B new) (~2e-6)
//   C: full 768-dim exact distance, folded into the running min
// NOTE (R9 lesson): do NOT fuse the finish via per-block agent-scope
// fences/atomics — on gfx950 each release/acquire at agent scope costs a
// bulk L2 writeback/invalidate (non-coherent per-XCD L2s); 4096 of them
// serialized to ~300us. The kernel boundary does ONE flush; keep 2 kernels.
#define THRESH 110.0f

__device__ __forceinline__ float sqd4(float4 a, float4 b) {
    float dx = a.x - b.x;
    float dy = a.y - b.y;
    float dz = a.z - b.z;
    float dw = a.w - b.w;
    return dx * dx + dy * dy + dz * dz + dw * dw;
}

// Kernel 1: 16 lanes per fact (seg = lane&15), 4 facts per pass
// (sub = lane>>4). Stage A prefetches ALL 4 pass-rows up-front (4
// independent float4 loads/lane -> one vmcnt drain instead of 4 exposed
// waits; indices clamped to nb-1, clamped duplicates excluded from the
// candidate mask by the f<nb predicate). Stage-B candidates are pulled
// 4-at-a-time from the wave-uniform mask and resolved in-wave; stage C is
// the exact 768-dim fallback. Every wave (live or dead) writes its dmin
// slot -> ws fully rewritten every call, no init kernel, no atomics.
__global__ __launch_bounds__(256, 8) void nkb_prefix_kernel(
    const float* __restrict__ rel,
    const float* __restrict__ arg1,
    const float* __restrict__ arg2,
    const float* __restrict__ fact_rel,
    const float* __restrict__ fact_arg1,
    const float* __restrict__ fact_arg2,
    const int* __restrict__ nb_facts,
    float* __restrict__ ws)
{
    const int b = blockIdx.x >> 5;        // / CHUNKS_PER_B
    const int chunk = blockIdx.x & 31;    // % CHUNKS_PER_B
    const int nb = nb_facts[b];
    const int tid = threadIdx.x;
    const int wave = tid >> 6;
    const int lane = tid & 63;
    const int sub = lane >> 4;   // which of the 4 facts in a pass/batch
    const int seg = lane & 15;   // float4 segment within a 64-dim half-prefix

    const int fbeg = chunk * FACTS_PER_BLOCK + wave * FACTS_PER_WAVE;
    float dmin = INFINITY;

    if (fbeg < nb) {
        const int fmax = nb - 1;  // nb >= 1 here
        // Query prefix: q0 covers dims [4seg,4seg+4) (stage A),
        //               q1 covers dims [64+4seg, 64+4seg+4) (stage B).
        const float4* qr = reinterpret_cast<const float4*>(rel + (size_t)b * NE);
        const float4 q0 = qr[seg];
        const float4 q1 = qr[seg + 16];

        const float4* fr = reinterpret_cast<const float4*>(fact_rel + (size_t)b * NF * NE);

        // ---- Stage A: 64-dim prefix, all 4 pass-rows prefetched up-front ----
        float4 P[NPASS];
        #pragma unroll
        for (int k = 0; k < NPASS; ++k) {
            const int f = min(fbeg + 4 * k + sub, fmax);
            P[k] = fr[(size_t)f * NF4 + seg];
        }

        unsigned int maskA = 0;  // bit p: fact fbeg+p survives stage A (uniform)
        #pragma unroll
        for (int k = 0; k < NPASS; ++k) {
            float acc = sqd4(q0, P[k]);
            #pragma unroll
            for (int s = 1; s < 16; s <<= 1) acc += __shfl_xor(acc, s);

            const bool cand = (acc <= THRESH) && (fbeg + 4 * k + sub < nb);
            const unsigned long long bal = __ballot(cand);
            const unsigned int bits =
                  (unsigned int)( (bal        & 1ull)
                               | ((bal >> 16) & 1ull) << 1
                               | ((bal >> 32) & 1ull) << 2
                               | ((bal >> 48) & 1ull) << 3);
            maskA |= bits << (4 * k);  // bit index 4k+sub
        }

        // ---- Stage B: 128-dim prefix for stage-A survivors, 4 at a time ----
        unsigned int maskB = 0;  // survivors of the 128-dim screen (uniform)
        while (maskA) {
            unsigned int m = maskA;
            const int i0 = __ffs(m) - 1; m &= m - 1;   // valid (loop guard)
            const int i1 = __ffs(m) - 1; m &= m - 1;   // may be -1
            const int i2 = __ffs(m) - 1; m &= m - 1;
            const int i3 = __ffs(m) - 1; m &= m - 1;
            maskA = m;

            const int idx = (sub == 0) ? i0 : (sub == 1) ? i1 : (sub == 2) ? i2 : i3;
            const bool act = (idx >= 0);
            const int f = fbeg + (act ? idx : i0);  // inactive lanes dup i0 (cache hit)
            const size_t base = (size_t)f * NF4 + seg;
            const float4 P0 = fr[base];        // stage-A bytes: L1/L2 hot
            const float4 P1 = fr[base + 16];   // new 256 B (dims 64..127)
            float acc = sqd4(q0, P0) + sqd4(q1, P1);
            #pragma unroll
            for (int s = 1; s < 16; s <<= 1) acc += __shfl_xor(acc, s);

            const bool candB = act && (acc <= THRESH);
            const unsigned long long bal = __ballot(candB);
            // Map group verdicts back to fact-bit positions (all uniform).
            if ( bal        & 1ull) maskB |= 1u << ((unsigned)i0 & 31u);
            if ((bal >> 16) & 1ull) maskB |= 1u << ((unsigned)i1 & 31u);
            if ((bal >> 32) & 1ull) maskB |= 1u << ((unsigned)i2 & 31u);
            if ((bal >> 48) & 1ull) maskB |= 1u << ((unsigned)i3 & 31u);
        }

        // ---- Stage C: exact full 768-dim distance (wave-uniform, ~never) ----
        if (maskB) {
            const float4* qa1 = reinterpret_cast<const float4*>(arg1 + (size_t)b * NE);
            const float4* qa2 = reinterpret_cast<const float4*>(arg2 + (size_t)b * NE);
            const float4* fa1 = reinterpret_cast<const float4*>(fact_arg1 + (size_t)b * NF * NE);
            const float4* fa2 = reinterpret_cast<const float4*>(fact_arg2 + (size_t)b * NF * NE);
            const float4 qfr  = qr [lane];
            const float4 qf1  = qa1[lane];
            const float4 qf2  = qa2[lane];
            while (maskB) {
                const int p = __ffs(maskB) - 1;
                maskB &= maskB - 1;
                const size_t base = (size_t)(fbeg + p) * NF4 + lane;
                float acc = sqd4(qfr, fr[base]) + sqd4(qf1, fa1[base]) + sqd4(qf2, fa2[base]);
                #pragma unroll
                for (int s = 1; s < 64; s <<= 1) acc += __shfl_xor(acc, s);
                dmin = fminf(dmin, acc);
            }
        }
    }

    // Per-wave slot write, [b][slot] layout: 512B contiguous per b so the
    // finish kernel reduces each b with one coalesced wave-read.
    if (lane == 0) ws[(size_t)b * NSLOT + chunk * WAVES_PER_BLOCK + wave] = dmin;
}

// Kernel 2: one wave per b. Two coalesced loads + 6-shuffle min + exp.
__global__ __launch_bounds__(256) void nkb_finish_kernel(
    const float* __restrict__ ws,
    float* __restrict__ out)
{
    const int wave = threadIdx.x >> 6;
    const int lane = threadIdx.x & 63;
    const int b = blockIdx.x * WAVES_PER_BLOCK + wave;  // 32 blocks x 4 waves

    float m = fminf(ws[(size_t)b * NSLOT + lane],
                    ws[(size_t)b * NSLOT + 64 + lane]);
    #pragma unroll
    for (int s = 1; s < 64; s <<= 1) m = fminf(m, __shfl_xor(m, s));
    if (lane == 0) {
        // No candidates anywhere (incl. nb==0): m=+inf -> output exactly 0.
        out[b] = isfinite(m) ? expf(-m) : 0.0f;
    }
}

extern "C" void kernel_launch(void* const* d_in, const int* in_sizes, int n_in,
                              void* d_out, int out_size, void* d_ws, size_t ws_size,
                              hipStream_t stream) {
    const float* rel       = (const float*)d_in[0];
    const float* arg1      = (const float*)d_in[1];
    const float* arg2      = (const float*)d_in[2];
    const float* fact_rel  = (const float*)d_in[3];
    const float* fact_arg1 = (const float*)d_in[4];
    const float* fact_arg2 = (const float*)d_in[5];
    const int*   nb_facts  = (const int*)d_in[6];
    float* out = (float*)d_out;
    float* ws  = (float*)d_ws;

    // 1) two-stage prefix screen (256B/fact + 256B for ~21% survivors)
    //    with fused exact fallback.
    const int grid = NB * CHUNKS_PER_B;  // 4096 blocks
    nkb_prefix_kernel<<<grid, 256, 0, stream>>>(rel, arg1, arg2,
                                                fact_rel, fact_arg1, fact_arg2,
                                                nb_facts, ws);

    // 2) wave-parallel reduce of 128 slots per b, exponentiate.
    nkb_finish_kernel<<<NB / WAVES_PER_BLOCK, 256, 0, stream>>>(ws, out);
}